// Round 6
// baseline (211.271 us; speedup 1.0000x reference)
//
#include <hip/hip_runtime.h>
#include <stdint.h>

typedef __attribute__((ext_vector_type(8))) short short8;
typedef __attribute__((ext_vector_type(4))) float f32x4;

#define K_DIM 4096
#define N_DIM 128
#define M_DIM 4096
#define MN ((size_t)M_DIM * N_DIM)

__device__ __forceinline__ uint16_t f2bf(float f) {
    uint32_t u = __float_as_uint(f);
    return (uint16_t)((u + 0x7FFFu + ((u >> 16) & 1u)) >> 16);
}

__device__ __forceinline__ short8 cvt8(const float4 lo, const float4 hi) {
    short8 r;
    r[0] = (short)f2bf(lo.x); r[1] = (short)f2bf(lo.y);
    r[2] = (short)f2bf(lo.z); r[3] = (short)f2bf(lo.w);
    r[4] = (short)f2bf(hi.x); r[5] = (short)f2bf(hi.y);
    r[6] = (short)f2bf(hi.z); r[7] = (short)f2bf(hi.w);
    return r;
}

// ---- prep: W f32 -> bf16 (3 matrices of 128 x 4096) ----
__global__ __launch_bounds__(256) void prep_kernel(
    const float* __restrict__ W0, const float* __restrict__ W1,
    const float* __restrict__ W2, uint16_t* __restrict__ Wb)
{
    int gid = blockIdx.x * 256 + threadIdx.x;   // 0 .. 196607
    int g = gid >> 16;                          // 65536 threads per matrix
    int e = (gid & 65535) * 8;
    const float* W = (g == 0) ? W0 : (g == 1) ? W1 : W2;
    float4 lo = *(const float4*)(W + e);
    float4 hi = *(const float4*)(W + e + 4);
    *(short8*)(Wb + (size_t)g * (N_DIM * K_DIM) + e) = cvt8(lo, hi);
}

// ---- fused: z_g = x_g @ W_g^T for ALL 3 g in one block, then aligned + loss
// in-register. BM=16, BN=64 (n-half), grid 512 = 256 mt x 2 nh, 256 thr.
// 4 waves split the 64 cols (16 each, 1 MFMA frag per g per K-half).
// LDS: dbuf x [g(3)][col(64)][slot(8) of 8 bf16] = 2 x 24 KB, staged via
// global_load_lds(16B) with the proven granule swizzle slot = k8 ^ (col&7)
// (0 conflicts measured R0-R4). A (f32) loaded to regs, 1-deep prefetch,
// cvt to bf16 in-register. XCD-paired swizzle: both n-halves of an m-tile
// land on the same XCD so the duplicate A reads and all Wb hit that L2.
__global__ __launch_bounds__(256, 2) void fused_kernel(
    const float* __restrict__ x0, const float* __restrict__ x1,
    const float* __restrict__ x2, const uint16_t* __restrict__ Wb,
    float* __restrict__ out, float* __restrict__ partials)
{
    __shared__ uint16_t lds[2][12288];   // 2 x 24 KiB

    const int tid  = threadIdx.x;
    const int lane = tid & 63;
    const int wv   = tid >> 6;

    const int lid = (blockIdx.x & 7) * 64 + (blockIdx.x >> 3);  // XCD-contig
    const int mt  = lid >> 1;
    const int nh  = lid & 1;

    const int c16 = lane & 15;
    const int qg  = lane >> 4;
    const int rowbase = mt * 16;

    // A sources: same 16 rows for all waves (dup merged in L1/L2)
    const float* ap0 = x0 + (size_t)(rowbase + c16) * K_DIM + qg * 8;
    const float* ap1 = x1 + (size_t)(rowbase + c16) * K_DIM + qg * 8;
    const float* ap2 = x2 + (size_t)(rowbase + c16) * K_DIM + qg * 8;
    const float* ap[3] = { ap0, ap1, ap2 };

    // stage sources: 6 calls x 256 thr x 16B = 48 KB... (24 KB per buffer)
    // dst elem e = c*2048 + tid*8 -> g = e>>12, col = (e>>6)&63, slot = (e>>3)&7
    const uint16_t* wsrc[6];
#pragma unroll
    for (int c = 0; c < 6; ++c) {
        const int e    = c * 2048 + tid * 8;
        const int g    = e >> 12;
        const int col  = (e >> 6) & 63;
        const int slot = (e >> 3) & 7;
        wsrc[c] = Wb + (size_t)g * (N_DIM * K_DIM)
                + (size_t)(nh * 64 + col) * K_DIM + (slot ^ (col & 7)) * 8;
    }

    f32x4 acc[3];
#pragma unroll
    for (int g = 0; g < 3; ++g) acc[g] = (f32x4)0.f;

    auto stage = [&](int p, int kbase) {
#pragma unroll
        for (int c = 0; c < 6; ++c) {
            __builtin_amdgcn_global_load_lds(
                (const __attribute__((address_space(1))) uint32_t*)(wsrc[c] + kbase),
                (__attribute__((address_space(3))) uint32_t*)&lds[p][c * 2048 + wv * 512],
                16, 0, 0);
        }
    };

    float4 a_cur[3][4], a_nxt[3][4];
    auto loadA = [&](float4 (*dst)[4], int kbase) {
#pragma unroll
        for (int g = 0; g < 3; ++g) {
            const float* a = ap[g] + kbase;
            dst[g][0] = *(const float4*)(a);
            dst[g][1] = *(const float4*)(a + 4);
            dst[g][2] = *(const float4*)(a + 32);
            dst[g][3] = *(const float4*)(a + 36);
        }
    };

    stage(0, 0);
    loadA(a_cur, 0);

    const int colw = wv * 16 + c16;          // block-local col of this lane
    const int cswz = c16 & 7;

    int p = 0;
    for (int kt = 0; kt < 64; ++kt) {
        __syncthreads();                     // buffer p staged; prev reads done
        if (kt + 1 < 64) {
            stage(p ^ 1, (kt + 1) * 64);
            loadA(a_nxt, (kt + 1) * 64);
        }
#pragma unroll
        for (int g = 0; g < 3; ++g) {
#pragma unroll
            for (int h = 0; h < 2; ++h) {
                short8 af = cvt8(a_cur[g][2 * h], a_cur[g][2 * h + 1]);
                const int boff = g * 4096 + colw * 64 + (((h * 4) + qg) ^ cswz) * 8;
                short8 bf = *(const short8*)&lds[p][boff];
                acc[g] = __builtin_amdgcn_mfma_f32_16x16x32_bf16(af, bf, acc[g], 0, 0, 0);
            }
        }
#pragma unroll
        for (int g = 0; g < 3; ++g)
#pragma unroll
            for (int i = 0; i < 4; ++i) a_cur[g][i] = a_nxt[g][i];
        p ^= 1;
    }

    // epilogue: aligned + loss, C/D layout col = lane&15, row = qg*4 + r
    float s = 0.f;
#pragma unroll
    for (int r = 0; r < 4; ++r) {
        const float z0 = acc[0][r], z1 = acc[1][r], z2 = acc[2][r];
        out[(size_t)(rowbase + qg * 4 + r) * N_DIM + nh * 64 + colw] =
            (z0 + z1 + z2) * (1.f / 3.f);
        const float d1 = z0 - z1, d2 = z0 - z2, d3 = z1 - z2;
        s += d1 * d1 + d2 * d2 + d3 * d3;
    }

#pragma unroll
    for (int off = 32; off > 0; off >>= 1) s += __shfl_xor(s, off);
    __shared__ float wsum[4];
    if (lane == 0) wsum[wv] = s;
    __syncthreads();
    if (tid == 0) partials[blockIdx.x] = wsum[0] + wsum[1] + wsum[2] + wsum[3];
}

__global__ __launch_bounds__(256) void finalize_kernel(
    const float* __restrict__ partials, float* __restrict__ out)
{
    const int tid = threadIdx.x;
    float s = partials[tid] + partials[tid + 256];
#pragma unroll
    for (int off = 32; off > 0; off >>= 1) s += __shfl_xor(s, off);
    __shared__ float wsum[4];
    if ((tid & 63) == 0) wsum[tid >> 6] = s;
    __syncthreads();
    if (tid == 0)
        out[MN] = (wsum[0] + wsum[1] + wsum[2] + wsum[3]) * (1.f / 12288.f) - 0.05f;
}

extern "C" void kernel_launch(void* const* d_in, const int* in_sizes, int n_in,
                              void* d_out, int out_size, void* d_ws, size_t ws_size,
                              hipStream_t stream)
{
    const float* x0 = (const float*)d_in[0];
    const float* x1 = (const float*)d_in[1];
    const float* x2 = (const float*)d_in[2];
    const float* W0 = (const float*)d_in[3];
    const float* W1 = (const float*)d_in[4];
    const float* W2 = (const float*)d_in[5];
    float* out = (float*)d_out;

    const size_t wb_bytes = (size_t)3 * N_DIM * K_DIM * sizeof(uint16_t);   // 3,145,728

    char* ws = (char*)d_ws;
    uint16_t* Wb       = (uint16_t*)ws;
    float*    partials = (float*)(ws + wb_bytes);

    prep_kernel    <<<768, 256, 0, stream>>>(W0, W1, W2, Wb);
    fused_kernel   <<<512, 256, 0, stream>>>(x0, x1, x2, Wb, out, partials);
    finalize_kernel<<<  1, 256, 0, stream>>>(partials, out);
}

// Round 7
// 59.469 us; speedup vs baseline: 3.5526x; 3.5526x over previous
//
#include <hip/hip_runtime.h>
#include <stdint.h>

typedef __attribute__((ext_vector_type(8))) short short8;
typedef __attribute__((ext_vector_type(4))) float f32x4;
typedef __attribute__((ext_vector_type(4))) uint32_t u32x4;

#define K_DIM 4096
#define N_DIM 128
#define M_DIM 4096
#define MN ((size_t)M_DIM * N_DIM)
#define NS 8
#define BK 32
#define FRAG_PER_SLAB ((size_t)64 * 8192)   // 64 m-tiles x (4 waves*64 lanes*32 vals)

__device__ __forceinline__ uint16_t f2bf(float f) {
    uint32_t u = __float_as_uint(f);
    return (uint16_t)((u + 0x7FFFu + ((u >> 16) & 1u)) >> 16);
}
__device__ __forceinline__ float bf2f(uint16_t h) {
    return __uint_as_float((uint32_t)h << 16);
}

__device__ __forceinline__ short8 cvt8(const float4 lo, const float4 hi) {
    short8 r;
    r[0] = (short)f2bf(lo.x); r[1] = (short)f2bf(lo.y);
    r[2] = (short)f2bf(lo.z); r[3] = (short)f2bf(lo.w);
    r[4] = (short)f2bf(hi.x); r[5] = (short)f2bf(hi.y);
    r[6] = (short)f2bf(hi.z); r[7] = (short)f2bf(hi.w);
    return r;
}

// ---- prep: W f32 -> bf16 (3 matrices of 128 x 4096) ----
__global__ __launch_bounds__(256) void prep_kernel(
    const float* __restrict__ W0, const float* __restrict__ W1,
    const float* __restrict__ W2, uint16_t* __restrict__ Wb)
{
    int gid = blockIdx.x * 256 + threadIdx.x;   // 0 .. 196607
    int g = gid >> 16;                          // 65536 threads per matrix
    int e = (gid & 65535) * 8;
    const float* W = (g == 0) ? W0 : (g == 1) ? W1 : W2;
    float4 lo = *(const float4*)(W + e);
    float4 hi = *(const float4*)(W + e + 4);
    *(short8*)(Wb + (size_t)g * (N_DIM * K_DIM) + e) = cvt8(lo, hi);
}

// ---- GEMM, K-split NS=8, BK=32: same data path as R0/R3 (granule-swizzled
// global_load_lds B-staging, in-reg A cvt, ds_read_b128 conflict-free) but
// LDS halved to 2x8KB so 6 blocks/CU are resident (launch_bounds(256,6));
// 1536 blocks = 6/CU = 24 waves/CU covering each other's barrier drains.
// Per iter per wave: 8 MFMA + 2 global_load_lds + 2 A-float4. NT=16.
// LDS layout per buffer: [col(128)][slot(4) of 8 bf16]; physical slot =
// logical slot ^ ((col>>1)&3)  (involution, applied on stage source AND read).
__global__ __launch_bounds__(256, 6) void gemm3_kernel(
    const float* __restrict__ x0, const float* __restrict__ x1,
    const float* __restrict__ x2, const uint16_t* __restrict__ Wb,
    uint16_t* __restrict__ zpart)
{
    __shared__ uint16_t lds[2][4096];   // 2 x 8 KiB

    const int tid  = threadIdx.x;
    const int lane = tid & 63;
    const int wv   = tid >> 6;

    const int per = (192 * NS) >> 3;                 // blocks per XCD (=192)
    const int lid = (blockIdx.x & 7) * per + (blockIdx.x >> 3);
    const int g   = lid / (NS * 64);
    const int rem = lid % (NS * 64);
    const int ks  = rem >> 6;
    const int mt  = rem & 63;
    const int k0  = ks * (K_DIM / NS);               // K-chunk of 512
    const int NT  = (K_DIM / NS) / BK;               // 16 iterations

    const float* x = (g == 0) ? x0 : (g == 1) ? x1 : x2;
    const uint16_t* Wg = Wb + (size_t)g * (N_DIM * K_DIM);

    const int c16 = lane & 15;
    const int qg  = lane >> 4;
    const int rowbase = mt * 64 + wv * 16;
    const float* aptr = x + (size_t)(rowbase + c16) * K_DIM + qg * 8 + k0;

    // staging source per call c: e = c*2048 + tid*8; col = e>>5, slot = (e>>3)&3
    const uint16_t* wsrc[2];
#pragma unroll
    for (int c = 0; c < 2; ++c) {
        const int e    = c * 2048 + tid * 8;
        const int col  = e >> 5;
        const int slot = (e >> 3) & 3;
        wsrc[c] = Wg + (size_t)col * K_DIM + (slot ^ ((col >> 1) & 3)) * 8 + k0;
    }

    f32x4 acc[8];
#pragma unroll
    for (int nf = 0; nf < 8; ++nf) acc[nf] = (f32x4)0.f;

    auto stage = [&](int p, int kbase) {
#pragma unroll
        for (int c = 0; c < 2; ++c) {
            __builtin_amdgcn_global_load_lds(
                (const __attribute__((address_space(1))) uint32_t*)(wsrc[c] + kbase),
                (__attribute__((address_space(3))) uint32_t*)&lds[p][c * 2048 + wv * 512],
                16, 0, 0);
        }
    };

    stage(0, 0);
    float4 a_cur[2], a_nxt[2];
    a_cur[0] = *(const float4*)(aptr);
    a_cur[1] = *(const float4*)(aptr + 4);

    const int cswz = (c16 >> 1) & 3;
    const int sswz = (qg ^ cswz) * 8;

    int p = 0;
    for (int kt = 0; kt < NT; ++kt) {
        const int kbase = kt * BK;
        __syncthreads();            // staging of buffer p (and A prefetch) complete
        if (kt + 1 < NT) {
            stage(p ^ 1, kbase + BK);
            const float* ap = aptr + kbase + BK;
            a_nxt[0] = *(const float4*)(ap);
            a_nxt[1] = *(const float4*)(ap + 4);
        }
        short8 af = cvt8(a_cur[0], a_cur[1]);
#pragma unroll
        for (int nf = 0; nf < 8; ++nf) {
            short8 bf = *(const short8*)&lds[p][(nf * 16 + c16) * 32 + sswz];
            acc[nf] = __builtin_amdgcn_mfma_f32_16x16x32_bf16(af, bf, acc[nf], 0, 0, 0);
        }
        a_cur[0] = a_nxt[0];
        a_cur[1] = a_nxt[1];
        p ^= 1;
    }

    // fragment-packed bf16 epilogue: idx = nf*4 + r, 32 vals per lane, 64B contiguous
    uint32_t dw[16];
#pragma unroll
    for (int nf = 0; nf < 8; ++nf) {
        dw[nf * 2]     = (uint32_t)f2bf(acc[nf][0]) | ((uint32_t)f2bf(acc[nf][1]) << 16);
        dw[nf * 2 + 1] = (uint32_t)f2bf(acc[nf][2]) | ((uint32_t)f2bf(acc[nf][3]) << 16);
    }
    uint16_t* zp = zpart + (size_t)(ks * 3 + g) * FRAG_PER_SLAB
                 + (size_t)mt * 8192 + (size_t)(wv * 64 + lane) * 32;
    uint32_t* zp32 = (uint32_t*)zp;
#pragma unroll
    for (int j = 0; j < 4; ++j) {
        u32x4 v = { dw[j * 4], dw[j * 4 + 1], dw[j * 4 + 2], dw[j * 4 + 3] };
        *(u32x4*)(zp32 + j * 4) = v;
    }
}

// ---- combine: sum 8 bf16 partials per (g, element) in fragment order,
// write aligned (scatter decode), per-block loss partials ----
__global__ __launch_bounds__(256) void combine_kernel(
    const uint16_t* __restrict__ zpart, float* __restrict__ out,
    float* __restrict__ partials)
{
    const int tid  = threadIdx.x;
    const int gtid = blockIdx.x * 256 + tid;        // 65536 threads
    const size_t F0 = (size_t)gtid * 8;             // 8 consecutive frag vals

    // decode fragment position
    const int idx_base = (int)(F0 & 31);            // 0,8,16,24
    const int lane = (int)((F0 >> 5) & 63);
    const int wv   = (int)((F0 >> 11) & 3);
    const int mt   = (int)(F0 >> 13);
    const int c16  = lane & 15;
    const int qg   = lane >> 4;
    const int rowb = mt * 64 + wv * 16 + qg * 4;

    float zs[3][8];
#pragma unroll
    for (int g = 0; g < 3; ++g)
#pragma unroll
        for (int v = 0; v < 8; ++v) zs[g][v] = 0.f;

#pragma unroll
    for (int ks = 0; ks < NS; ++ks) {
#pragma unroll
        for (int g = 0; g < 3; ++g) {
            const short8 pv = *(const short8*)(zpart + (size_t)(ks * 3 + g) * FRAG_PER_SLAB + F0);
#pragma unroll
            for (int v = 0; v < 8; ++v) zs[g][v] += bf2f((uint16_t)pv[v]);
        }
    }

    float s = 0.f;
#pragma unroll
    for (int v = 0; v < 8; ++v) {
        const float a = zs[0][v], b = zs[1][v], c = zs[2][v];
        const int idx = idx_base + v;
        const int nf = idx >> 2, r = idx & 3;
        out[(size_t)(rowb + r) * N_DIM + nf * 16 + c16] = (a + b + c) * (1.f / 3.f);
        const float d1 = a - b, d2 = a - c, d3 = b - c;
        s += d1 * d1 + d2 * d2 + d3 * d3;
    }

#pragma unroll
    for (int off = 32; off > 0; off >>= 1) s += __shfl_xor(s, off);
    __shared__ float wsum[4];
    if ((tid & 63) == 0) wsum[tid >> 6] = s;
    __syncthreads();
    if (tid == 0) partials[blockIdx.x] = wsum[0] + wsum[1] + wsum[2] + wsum[3];
}

__global__ __launch_bounds__(256) void finalize_kernel(
    const float* __restrict__ partials, float* __restrict__ out)
{
    const int tid = threadIdx.x;
    float s = partials[tid];
#pragma unroll
    for (int off = 32; off > 0; off >>= 1) s += __shfl_xor(s, off);
    __shared__ float wsum[4];
    if ((tid & 63) == 0) wsum[tid >> 6] = s;
    __syncthreads();
    if (tid == 0)
        out[MN] = (wsum[0] + wsum[1] + wsum[2] + wsum[3]) * (1.f / 12288.f) - 0.05f;
}

extern "C" void kernel_launch(void* const* d_in, const int* in_sizes, int n_in,
                              void* d_out, int out_size, void* d_ws, size_t ws_size,
                              hipStream_t stream)
{
    const float* x0 = (const float*)d_in[0];
    const float* x1 = (const float*)d_in[1];
    const float* x2 = (const float*)d_in[2];
    const float* W0 = (const float*)d_in[3];
    const float* W1 = (const float*)d_in[4];
    const float* W2 = (const float*)d_in[5];
    float* out = (float*)d_out;

    const size_t zpart_bytes = (size_t)NS * 3 * FRAG_PER_SLAB * sizeof(uint16_t); // 25,165,824
    const size_t wb_bytes    = (size_t)3 * N_DIM * K_DIM * sizeof(uint16_t);      //  3,145,728

    char* ws = (char*)d_ws;
    uint16_t* zpart    = (uint16_t*)ws;
    uint16_t* Wb       = (uint16_t*)(ws + zpart_bytes);
    float*    partials = (float*)(ws + zpart_bytes + wb_bytes);

    prep_kernel    <<< 768, 256, 0, stream>>>(W0, W1, W2, Wb);
    gemm3_kernel   <<<1536, 256, 0, stream>>>(x0, x1, x2, Wb, zpart);
    combine_kernel <<< 256, 256, 0, stream>>>(zpart, out, partials);
    finalize_kernel<<<   1, 256, 0, stream>>>(partials, out);
}

// Round 8
// 55.187 us; speedup vs baseline: 3.8283x; 1.0776x over previous
//
#include <hip/hip_runtime.h>
#include <stdint.h>

typedef __attribute__((ext_vector_type(8))) short short8;
typedef __attribute__((ext_vector_type(4))) float f32x4;
typedef __attribute__((ext_vector_type(4))) uint32_t u32x4;

#define K_DIM 4096
#define N_DIM 128
#define M_DIM 4096
#define MN ((size_t)M_DIM * N_DIM)
#define NS 4
#define BK 32
#define NTI 32                      // (K_DIM/NS)/BK iterations per block
#define FRAG_PER_SLAB MN

__device__ __forceinline__ uint16_t f2bf(float f) {
    uint32_t u = __float_as_uint(f);
    return (uint16_t)((u + 0x7FFFu + ((u >> 16) & 1u)) >> 16);
}
__device__ __forceinline__ float bf2f(uint16_t h) {
    return __uint_as_float((uint32_t)h << 16);
}

__device__ __forceinline__ short8 cvt8(const float4 lo, const float4 hi) {
    short8 r;
    r[0] = (short)f2bf(lo.x); r[1] = (short)f2bf(lo.y);
    r[2] = (short)f2bf(lo.z); r[3] = (short)f2bf(lo.w);
    r[4] = (short)f2bf(hi.x); r[5] = (short)f2bf(hi.y);
    r[6] = (short)f2bf(hi.z); r[7] = (short)f2bf(hi.w);
    return r;
}

// ---- prep: W f32 -> bf16 (3 matrices of 128 x 4096) ----
__global__ __launch_bounds__(256) void prep_kernel(
    const float* __restrict__ W0, const float* __restrict__ W1,
    const float* __restrict__ W2, uint16_t* __restrict__ Wb)
{
    int gid = blockIdx.x * 256 + threadIdx.x;   // 0 .. 196607
    int g = gid >> 16;                          // 65536 threads per matrix
    int e = (gid & 65535) * 8;
    const float* W = (g == 0) ? W0 : (g == 1) ? W1 : W2;
    float4 lo = *(const float4*)(W + e);
    float4 hi = *(const float4*)(W + e + 4);
    *(short8*)(Wb + (size_t)g * (N_DIM * K_DIM) + e) = cvt8(lo, hi);
}

// ---- GEMM, K-split NS=4, BK=32, 4-deep LDS pipeline with counted vmcnt ----
// Data path identical to R6 (verified): granule-swizzled global_load_lds
// B-staging (phys slot = slot ^ ((col>>1)&3)), in-reg A f32->bf16, 8 MFMA +
// 8 ds_read_b128 per iter per wave, 0 bank conflicts. NEW: T3/T4 schedule —
// iter kt reads buf[kt&3]; after ONE raw s_barrier it issues the 4-vmem batch
// (2 global_load_lds + 2 A float4) for iter kt+2, then waits vmcnt(8) so only
// the 2 newest batches stay in flight (batch kt-2 = this iter's data landed).
// Never vmcnt(0) in the main loop: the HBM pipe never drains. Buffer overwrite
// safety: buf[(kt+2)&3] was last read at iter kt-2, whose ds_reads drained at
// the lgkmcnt(0)+barrier of iter kt-1 — one full iteration of slack.
__global__ __launch_bounds__(256, 3) void gemm3_kernel(
    const float* __restrict__ x0, const float* __restrict__ x1,
    const float* __restrict__ x2, const uint16_t* __restrict__ Wb,
    uint16_t* __restrict__ zpart)
{
    __shared__ uint16_t lds[4][4096];   // 4 x 8 KiB: [col(128)][granule(4) of 8 bf16]

    const int tid  = threadIdx.x;
    const int lane = tid & 63;
    const int wv   = tid >> 6;

    const int lid = (blockIdx.x & 7) * 96 + (blockIdx.x >> 3);   // XCD-contig
    const int g   = lid >> 8;
    const int rem = lid & 255;
    const int ks  = rem >> 6;
    const int mt  = rem & 63;
    const int k0  = ks * (K_DIM / NS);               // K-chunk of 1024

    const float* x = (g == 0) ? x0 : (g == 1) ? x1 : x2;
    const uint16_t* Wg = Wb + (size_t)g * (N_DIM * K_DIM);

    const int c16 = lane & 15;
    const int qg  = lane >> 4;
    const int rowbase = mt * 64 + wv * 16;
    const float* aptr = x + (size_t)(rowbase + c16) * K_DIM + qg * 8 + k0;

    // staging sources (R6-verified): e = c*2048 + tid*8; col = e>>5, slot=(e>>3)&3
    const uint16_t* wsrc0;
    const uint16_t* wsrc1;
    {
        const int e0 = tid * 8, e1 = 2048 + tid * 8;
        const int col0 = e0 >> 5, s0 = (e0 >> 3) & 3;
        const int col1 = e1 >> 5, s1 = (e1 >> 3) & 3;
        wsrc0 = Wg + (size_t)col0 * K_DIM + (s0 ^ ((col0 >> 1) & 3)) * 8 + k0;
        wsrc1 = Wg + (size_t)col1 * K_DIM + (s1 ^ ((col1 >> 1) & 3)) * 8 + k0;
    }

    const int cswz = (c16 >> 1) & 3;
    const int sswz = (qg ^ cswz) * 8;

    f32x4 acc[8];
#pragma unroll
    for (int nf = 0; nf < 8; ++nf) acc[nf] = (f32x4)0.f;

    float4 areg[4][2];

#define STAGE(B, KB) do {                                                      \
    __builtin_amdgcn_global_load_lds(                                          \
        (const __attribute__((address_space(1))) uint32_t*)(wsrc0 + (KB)),     \
        (__attribute__((address_space(3))) uint32_t*)&lds[B][wv * 512],        \
        16, 0, 0);                                                             \
    __builtin_amdgcn_global_load_lds(                                          \
        (const __attribute__((address_space(1))) uint32_t*)(wsrc1 + (KB)),     \
        (__attribute__((address_space(3))) uint32_t*)&lds[B][2048 + wv * 512], \
        16, 0, 0);                                                             \
  } while (0)

#define BATCH(B, KB) do {                                                      \
    STAGE(B, KB);                                                              \
    areg[B][0] = *(const float4*)(aptr + (KB));                                \
    areg[B][1] = *(const float4*)(aptr + (KB) + 4);                            \
  } while (0)

#define ITER(SLOT, KT, VM, ISSUE) do {                                         \
    asm volatile("s_waitcnt lgkmcnt(0)" ::: "memory");                         \
    asm volatile("s_barrier" ::: "memory");                                    \
    if (ISSUE) { BATCH((((SLOT) + 2) & 3), (((KT) + 2) * BK)); }               \
    asm volatile("s_waitcnt vmcnt(%0)" :: "i"(VM) : "memory");                 \
    {                                                                          \
        short8 af = cvt8(areg[SLOT][0], areg[SLOT][1]);                        \
        _Pragma("unroll")                                                      \
        for (int nf = 0; nf < 8; ++nf) {                                       \
            short8 bf = *(const short8*)&lds[SLOT][(nf * 16 + c16) * 32 + sswz]; \
            acc[nf] = __builtin_amdgcn_mfma_f32_16x16x32_bf16(af, bf, acc[nf], 0, 0, 0); \
        }                                                                      \
    }                                                                          \
  } while (0)

    // prologue: stage iters 0 and 1
    BATCH(0, 0);
    BATCH(1, BK);

#pragma unroll
    for (int kt = 0; kt < 28; kt += 4) {
        ITER(0, kt + 0, 8, true);
        ITER(1, kt + 1, 8, true);
        ITER(2, kt + 2, 8, true);
        ITER(3, kt + 3, 8, true);
    }
    ITER(0, 28, 8, true);     // stages iter 30 -> buf2
    ITER(1, 29, 8, true);     // stages iter 31 -> buf3
    ITER(2, 30, 4, false);
    ITER(3, 31, 0, false);

#undef ITER
#undef BATCH
#undef STAGE

    // fragment-packed bf16 epilogue (R4/R6-verified): 4 x 16B contiguous stores
    uint32_t dw[16];
#pragma unroll
    for (int nf = 0; nf < 8; ++nf) {
        dw[nf * 2]     = (uint32_t)f2bf(acc[nf][0]) | ((uint32_t)f2bf(acc[nf][1]) << 16);
        dw[nf * 2 + 1] = (uint32_t)f2bf(acc[nf][2]) | ((uint32_t)f2bf(acc[nf][3]) << 16);
    }
    uint16_t* zp = zpart + (size_t)(ks * 3 + g) * FRAG_PER_SLAB
                 + (size_t)mt * 8192 + (size_t)(wv * 64 + lane) * 32;
    uint32_t* zp32 = (uint32_t*)zp;
#pragma unroll
    for (int j = 0; j < 4; ++j) {
        u32x4 v = { dw[j * 4], dw[j * 4 + 1], dw[j * 4 + 2], dw[j * 4 + 3] };
        *(u32x4*)(zp32 + j * 4) = v;
    }
}

// ---- combine: sum NS=4 bf16 partials per (g, element) in fragment order,
// write aligned (scatter decode), per-block loss partials ----
__global__ __launch_bounds__(256) void combine_kernel(
    const uint16_t* __restrict__ zpart, float* __restrict__ out,
    float* __restrict__ partials)
{
    const int tid  = threadIdx.x;
    const int gtid = blockIdx.x * 256 + tid;        // 65536 threads
    const size_t F0 = (size_t)gtid * 8;             // 8 consecutive frag vals

    const int idx_base = (int)(F0 & 31);            // 0,8,16,24
    const int lane = (int)((F0 >> 5) & 63);
    const int wv   = (int)((F0 >> 11) & 3);
    const int mt   = (int)(F0 >> 13);
    const int c16  = lane & 15;
    const int qg   = lane >> 4;
    const int rowb = mt * 64 + wv * 16 + qg * 4;

    float zs[3][8];
#pragma unroll
    for (int g = 0; g < 3; ++g)
#pragma unroll
        for (int v = 0; v < 8; ++v) zs[g][v] = 0.f;

#pragma unroll
    for (int ks = 0; ks < NS; ++ks) {
#pragma unroll
        for (int g = 0; g < 3; ++g) {
            const short8 pv = *(const short8*)(zpart + (size_t)(ks * 3 + g) * FRAG_PER_SLAB + F0);
#pragma unroll
            for (int v = 0; v < 8; ++v) zs[g][v] += bf2f((uint16_t)pv[v]);
        }
    }

    float s = 0.f;
#pragma unroll
    for (int v = 0; v < 8; ++v) {
        const float a = zs[0][v], b = zs[1][v], c = zs[2][v];
        const int idx = idx_base + v;
        const int nf = idx >> 2, r = idx & 3;
        out[(size_t)(rowb + r) * N_DIM + nf * 16 + c16] = (a + b + c) * (1.f / 3.f);
        const float d1 = a - b, d2 = a - c, d3 = b - c;
        s += d1 * d1 + d2 * d2 + d3 * d3;
    }

#pragma unroll
    for (int off = 32; off > 0; off >>= 1) s += __shfl_xor(s, off);
    __shared__ float wsum[4];
    if ((tid & 63) == 0) wsum[tid >> 6] = s;
    __syncthreads();
    if (tid == 0) partials[blockIdx.x] = wsum[0] + wsum[1] + wsum[2] + wsum[3];
}

__global__ __launch_bounds__(256) void finalize_kernel(
    const float* __restrict__ partials, float* __restrict__ out)
{
    const int tid = threadIdx.x;
    float s = partials[tid];
#pragma unroll
    for (int off = 32; off > 0; off >>= 1) s += __shfl_xor(s, off);
    __shared__ float wsum[4];
    if ((tid & 63) == 0) wsum[tid >> 6] = s;
    __syncthreads();
    if (tid == 0)
        out[MN] = (wsum[0] + wsum[1] + wsum[2] + wsum[3]) * (1.f / 12288.f) - 0.05f;
}

extern "C" void kernel_launch(void* const* d_in, const int* in_sizes, int n_in,
                              void* d_out, int out_size, void* d_ws, size_t ws_size,
                              hipStream_t stream)
{
    const float* x0 = (const float*)d_in[0];
    const float* x1 = (const float*)d_in[1];
    const float* x2 = (const float*)d_in[2];
    const float* W0 = (const float*)d_in[3];
    const float* W1 = (const float*)d_in[4];
    const float* W2 = (const float*)d_in[5];
    float* out = (float*)d_out;

    const size_t zpart_bytes = (size_t)NS * 3 * FRAG_PER_SLAB * sizeof(uint16_t); // 12,582,912
    const size_t wb_bytes    = (size_t)3 * N_DIM * K_DIM * sizeof(uint16_t);      //  3,145,728

    char* ws = (char*)d_ws;
    uint16_t* zpart    = (uint16_t*)ws;
    uint16_t* Wb       = (uint16_t*)(ws + zpart_bytes);
    float*    partials = (float*)(ws + zpart_bytes + wb_bytes);

    prep_kernel    <<<768, 256, 0, stream>>>(W0, W1, W2, Wb);
    gemm3_kernel   <<<768, 256, 0, stream>>>(x0, x1, x2, Wb, zpart);
    combine_kernel <<<256, 256, 0, stream>>>(zpart, out, partials);
    finalize_kernel<<<  1, 256, 0, stream>>>(partials, out);
}

// Round 9
// 51.990 us; speedup vs baseline: 4.0637x; 1.0615x over previous
//
#include <hip/hip_runtime.h>
#include <stdint.h>

typedef __attribute__((ext_vector_type(8))) short short8;
typedef __attribute__((ext_vector_type(4))) float f32x4;
typedef __attribute__((ext_vector_type(4))) uint32_t u32x4;

#define K_DIM 4096
#define N_DIM 128
#define M_DIM 4096
#define MN ((size_t)M_DIM * N_DIM)
#define NS 4
#define BK 64
#define FRAG_PER_SLAB MN

__device__ __forceinline__ uint16_t f2bf(float f) {
    uint32_t u = __float_as_uint(f);
    return (uint16_t)((u + 0x7FFFu + ((u >> 16) & 1u)) >> 16);
}
__device__ __forceinline__ float bf2f(uint16_t h) {
    return __uint_as_float((uint32_t)h << 16);
}

__device__ __forceinline__ short8 cvt8(const float4 lo, const float4 hi) {
    short8 r;
    r[0] = (short)f2bf(lo.x); r[1] = (short)f2bf(lo.y);
    r[2] = (short)f2bf(lo.z); r[3] = (short)f2bf(lo.w);
    r[4] = (short)f2bf(hi.x); r[5] = (short)f2bf(hi.y);
    r[6] = (short)f2bf(hi.z); r[7] = (short)f2bf(hi.w);
    return r;
}

// ---- prep: W f32 -> bf16 (3 matrices of 128 x 4096) ----
__global__ __launch_bounds__(256) void prep_kernel(
    const float* __restrict__ W0, const float* __restrict__ W1,
    const float* __restrict__ W2, uint16_t* __restrict__ Wb)
{
    int gid = blockIdx.x * 256 + threadIdx.x;   // 0 .. 196607
    int g = gid >> 16;                          // 65536 threads per matrix
    int e = (gid & 65535) * 8;
    const float* W = (g == 0) ? W0 : (g == 1) ? W1 : W2;
    float4 lo = *(const float4*)(W + e);
    float4 hi = *(const float4*)(W + e + 4);
    *(short8*)(Wb + (size_t)g * (N_DIM * K_DIM) + e) = cvt8(lo, hi);
}

// ---- GEMM, K-split NS=4, BK=64 (R3's best-measured per-iter shape: 16 MFMA
// + 8 ds_read_b128 + 4 global_load_lds per wave) with R7's verified counted-
// vmcnt schedule at depth 2 over THREE 16KB LDS buffers (48 KB -> 3 blocks/CU).
// Iter kt: lgkmcnt(0); s_barrier; issue batch kt+2 into buf (kt+2)%3
// (8 vmem: 4 stage + 4 A-float4); s_waitcnt vmcnt(16) -- the 2 newest batches
// stay in flight, batch kt (this iter's data) has landed. Never vmcnt(0) in
// the main loop. Buffer safety: buf (kt+2)%3 was last read at iter kt-1; those
// ds_reads drained at this iter's lgkmcnt(0)+barrier, before the issue.
__global__ __launch_bounds__(256, 3) void gemm3_kernel(
    const float* __restrict__ x0, const float* __restrict__ x1,
    const float* __restrict__ x2, const uint16_t* __restrict__ Wb,
    uint16_t* __restrict__ zpart)
{
    __shared__ uint16_t lds[3][8192];   // 3 x 16 KiB: [col(128)][granule(8) of 8 bf16]

    const int tid  = threadIdx.x;
    const int lane = tid & 63;
    const int wv   = tid >> 6;

    const int lid = (blockIdx.x & 7) * 96 + (blockIdx.x >> 3);   // XCD-contig
    const int g   = lid >> 8;
    const int rem = lid & 255;
    const int ks  = rem >> 6;
    const int mt  = rem & 63;
    const int k0  = ks * (K_DIM / NS);               // K-chunk of 1024, NT=16

    const float* x = (g == 0) ? x0 : (g == 1) ? x1 : x2;
    const uint16_t* Wg = Wb + (size_t)g * (N_DIM * K_DIM);

    const int c16 = lane & 15;
    const int qg  = lane >> 4;
    const int rowbase = mt * 64 + wv * 16;
    const float* aptr = x + (size_t)(rowbase + c16) * K_DIM + qg * 8 + k0;

    // staging sources (R0/R3-verified): col = c*32 + (tid>>3), slot = tid&7,
    // granule = slot ^ (col&7)
    const int t8 = tid >> 3, slot = tid & 7;
    const uint16_t* wsrc[4];
#pragma unroll
    for (int c = 0; c < 4; ++c) {
        int col = c * 32 + t8;
        wsrc[c] = Wg + (size_t)col * K_DIM + (slot ^ (col & 7)) * 8 + k0;
    }

    f32x4 acc[8];
#pragma unroll
    for (int nf = 0; nf < 8; ++nf) acc[nf] = (f32x4)0.f;

    float4 areg[3][4];

#define STAGE(B, KB) do {                                                      \
    _Pragma("unroll")                                                          \
    for (int c = 0; c < 4; ++c) {                                              \
        __builtin_amdgcn_global_load_lds(                                      \
            (const __attribute__((address_space(1))) uint32_t*)(wsrc[c] + (KB)), \
            (__attribute__((address_space(3))) uint32_t*)&lds[B][c * 2048 + wv * 512], \
            16, 0, 0);                                                         \
    }                                                                          \
  } while (0)

#define BATCH(B, KB) do {                                                      \
    STAGE(B, KB);                                                              \
    areg[B][0] = *(const float4*)(aptr + (KB));                                \
    areg[B][1] = *(const float4*)(aptr + (KB) + 4);                            \
    areg[B][2] = *(const float4*)(aptr + (KB) + 32);                           \
    areg[B][3] = *(const float4*)(aptr + (KB) + 36);                           \
  } while (0)

#define ITER(SLOT, KT, VM, ISSUE) do {                                         \
    asm volatile("s_waitcnt lgkmcnt(0)" ::: "memory");                         \
    asm volatile("s_barrier" ::: "memory");                                    \
    if (ISSUE) { BATCH((((SLOT) + 2) % 3), (((KT) + 2) * BK)); }               \
    asm volatile("s_waitcnt vmcnt(%0)" :: "i"(VM) : "memory");                 \
    _Pragma("unroll")                                                          \
    for (int h = 0; h < 2; ++h) {                                              \
        short8 af = cvt8(areg[SLOT][2 * h], areg[SLOT][2 * h + 1]);            \
        const int boff = c16 * 64 + (((h * 4) + qg) ^ (lane & 7)) * 8;         \
        _Pragma("unroll")                                                      \
        for (int nf = 0; nf < 8; ++nf) {                                       \
            short8 bf = *(const short8*)&lds[SLOT][nf * 1024 + boff];          \
            acc[nf] = __builtin_amdgcn_mfma_f32_16x16x32_bf16(af, bf, acc[nf], 0, 0, 0); \
        }                                                                      \
    }                                                                          \
  } while (0)

    // prologue: batches for iters 0 and 1
    BATCH(0, 0);
    BATCH(1, BK);

#pragma unroll
    for (int kt = 0; kt < 12; kt += 3) {
        ITER(0, kt + 0, 16, true);
        ITER(1, kt + 1, 16, true);
        ITER(2, kt + 2, 16, true);
    }
    ITER(0, 12, 16, true);    // issues kt14 -> buf2
    ITER(1, 13, 16, true);    // issues kt15 -> buf0
    ITER(2, 14,  8, false);
    ITER(0, 15,  0, false);

#undef ITER
#undef BATCH
#undef STAGE

    // fragment-packed bf16 epilogue (R4/R7-verified): 4 x 16B contiguous stores
    uint32_t dw[16];
#pragma unroll
    for (int nf = 0; nf < 8; ++nf) {
        dw[nf * 2]     = (uint32_t)f2bf(acc[nf][0]) | ((uint32_t)f2bf(acc[nf][1]) << 16);
        dw[nf * 2 + 1] = (uint32_t)f2bf(acc[nf][2]) | ((uint32_t)f2bf(acc[nf][3]) << 16);
    }
    uint16_t* zp = zpart + (size_t)(ks * 3 + g) * FRAG_PER_SLAB
                 + (size_t)mt * 8192 + (size_t)(wv * 64 + lane) * 32;
    uint32_t* zp32 = (uint32_t*)zp;
#pragma unroll
    for (int j = 0; j < 4; ++j) {
        u32x4 v = { dw[j * 4], dw[j * 4 + 1], dw[j * 4 + 2], dw[j * 4 + 3] };
        *(u32x4*)(zp32 + j * 4) = v;
    }
}

// ---- combine: sum NS=4 bf16 partials per (g, element) in fragment order,
// write aligned (scatter decode), per-block loss partials ----
__global__ __launch_bounds__(256) void combine_kernel(
    const uint16_t* __restrict__ zpart, float* __restrict__ out,
    float* __restrict__ partials)
{
    const int tid  = threadIdx.x;
    const int gtid = blockIdx.x * 256 + tid;        // 65536 threads
    const size_t F0 = (size_t)gtid * 8;             // 8 consecutive frag vals

    const int idx_base = (int)(F0 & 31);            // 0,8,16,24
    const int lane = (int)((F0 >> 5) & 63);
    const int wv   = (int)((F0 >> 11) & 3);
    const int mt   = (int)(F0 >> 13);
    const int c16  = lane & 15;
    const int qg   = lane >> 4;
    const int rowb = mt * 64 + wv * 16 + qg * 4;

    float zs[3][8];
#pragma unroll
    for (int g = 0; g < 3; ++g)
#pragma unroll
        for (int v = 0; v < 8; ++v) zs[g][v] = 0.f;

#pragma unroll
    for (int ks = 0; ks < NS; ++ks) {
#pragma unroll
        for (int g = 0; g < 3; ++g) {
            const short8 pv = *(const short8*)(zpart + (size_t)(ks * 3 + g) * FRAG_PER_SLAB + F0);
#pragma unroll
            for (int v = 0; v < 8; ++v) zs[g][v] += bf2f((uint16_t)pv[v]);
        }
    }

    float s = 0.f;
#pragma unroll
    for (int v = 0; v < 8; ++v) {
        const float a = zs[0][v], b = zs[1][v], c = zs[2][v];
        const int idx = idx_base + v;
        const int nf = idx >> 2, r = idx & 3;
        out[(size_t)(rowb + r) * N_DIM + nf * 16 + c16] = (a + b + c) * (1.f / 3.f);
        const float d1 = a - b, d2 = a - c, d3 = b - c;
        s += d1 * d1 + d2 * d2 + d3 * d3;
    }

#pragma unroll
    for (int off = 32; off > 0; off >>= 1) s += __shfl_xor(s, off);
    __shared__ float wsum[4];
    if ((tid & 63) == 0) wsum[tid >> 6] = s;
    __syncthreads();
    if (tid == 0) partials[blockIdx.x] = wsum[0] + wsum[1] + wsum[2] + wsum[3];
}

__global__ __launch_bounds__(256) void finalize_kernel(
    const float* __restrict__ partials, float* __restrict__ out)
{
    const int tid = threadIdx.x;
    float s = partials[tid];
#pragma unroll
    for (int off = 32; off > 0; off >>= 1) s += __shfl_xor(s, off);
    __shared__ float wsum[4];
    if ((tid & 63) == 0) wsum[tid >> 6] = s;
    __syncthreads();
    if (tid == 0)
        out[MN] = (wsum[0] + wsum[1] + wsum[2] + wsum[3]) * (1.f / 12288.f) - 0.05f;
}

extern "C" void kernel_launch(void* const* d_in, const int* in_sizes, int n_in,
                              void* d_out, int out_size, void* d_ws, size_t ws_size,
                              hipStream_t stream)
{
    const float* x0 = (const float*)d_in[0];
    const float* x1 = (const float*)d_in[1];
    const float* x2 = (const float*)d_in[2];
    const float* W0 = (const float*)d_in[3];
    const float* W1 = (const float*)d_in[4];
    const float* W2 = (const float*)d_in[5];
    float* out = (float*)d_out;

    const size_t zpart_bytes = (size_t)NS * 3 * FRAG_PER_SLAB * sizeof(uint16_t); // 12,582,912
    const size_t wb_bytes    = (size_t)3 * N_DIM * K_DIM * sizeof(uint16_t);      //  3,145,728

    char* ws = (char*)d_ws;
    uint16_t* zpart    = (uint16_t*)ws;
    uint16_t* Wb       = (uint16_t*)(ws + zpart_bytes);
    float*    partials = (float*)(ws + zpart_bytes + wb_bytes);

    prep_kernel    <<<768, 256, 0, stream>>>(W0, W1, W2, Wb);
    gemm3_kernel   <<<768, 256, 0, stream>>>(x0, x1, x2, Wb, zpart);
    combine_kernel <<<256, 256, 0, stream>>>(zpart, out, partials);
    finalize_kernel<<<  1, 256, 0, stream>>>(partials, out);
}